// Round 4
// baseline (2053.640 us; speedup 1.0000x reference)
//
#include <hip/hip_runtime.h>
#include <stdint.h>

#define D_    10000
#define DP1   10001
#define NPAD2 10240      // 40 * 256 (padded vocab rows for GEMM1, N-tile 256)
#define H_    1024
#define BL    4096       // B * L
#define CANDS 1024       // candidate list capacity (p > 1e-7 of mass; typ. 2-6)

typedef float  f32x4  __attribute__((ext_vector_type(4)));
typedef __bf16 bf16x8 __attribute__((ext_vector_type(8)));
typedef unsigned short u16;
typedef u16    u16x8  __attribute__((ext_vector_type(8)));

// ---------- bf16 helpers (round-to-nearest-even) ----------
__device__ __forceinline__ u16 f2bf(float x) {
    union { float f; unsigned u; } v; v.f = x;
    unsigned r = v.u + 0x7FFFu + ((v.u >> 16) & 1u);
    return (u16)(r >> 16);
}
__device__ __forceinline__ float bf2f(u16 b) {
    union { float f; unsigned u; } v; v.u = ((unsigned)b) << 16;
    return v.f;
}

// async global -> LDS, 16B per lane (HW: wave-uniform base + lane*16)
#define GLOAD_LDS16(gsrc, ldst)                                             \
    __builtin_amdgcn_global_load_lds(                                       \
        (__attribute__((address_space(1))) void*)(void*)(gsrc),             \
        (__attribute__((address_space(3))) void*)(void*)(ldst), 16, 0, 0)

// History:
// R3: LDS chunk swizzle -> SQ_LDS_BANK_CONFLICT 2.07e7 -> 0.
// R6: 2-deep prefetch + counted vmcnt: occupancy 35->22%, dur flat.
// R7: 256^2 tile + 4-phase: REGRESSED (268us). Reverted.
// R8: sparse-gather epilogue replaced gemm2 pipeline: 692->648us, absmax
//   0.0313->0.0156 (fp32 gather more accurate than bf16 GEMM2).
// R9 post-mortem: "46% MfmaUtil" is a derived-counter artifact. Raw: 15.7M
//   MFMA / 1024 SIMD * 4.85cy = 74.5Kcy vs measured 595Kcy -> real MFMA
//   busy 12.5%, LDS busy 27%. gemm1 is LATENCY/BARRIER-bound at 1 block/CU
//   (96KB LDS). Fix: lo operands bypass LDS (per-lane global loads, L2-hot
//   panels) -> LDS 48KB hi-only dbuf -> 2 blocks/CU; phase1 = 16 hh MFMA,
//   phase2 = 32 hl+lh MFMA (lo regs get a full phase to land).
//   softmax_gather: row chunks in registers (10x f32x4), LDS only for
//   reductions + candidate list (8KB -> ~8 blocks/CU).

// ---------- prep: split fp32 -> bf16 hi + lo ----------
__global__ __launch_bounds__(256)
void split_desc_k(const float* __restrict__ desc, u16* __restrict__ hi, u16* __restrict__ lo) {
    size_t i = (size_t)blockIdx.x * 256 + threadIdx.x;   // exactly BL*H_
    float x = desc[i];
    u16 h = f2bf(x);
    hi[i] = h;
    lo[i] = f2bf(x - bf2f(h));
}

__global__ __launch_bounds__(256)
void split_fv_k(const float* __restrict__ vocab, const float* __restrict__ defe,
                u16* __restrict__ hi, u16* __restrict__ lo) {
    size_t i = (size_t)blockIdx.x * 256 + threadIdx.x;   // exactly NPAD2*H_
    int d = (int)(i >> 10);
    int h = (int)(i & 1023);
    float x = 0.f;
    if (d < D_)       x = vocab[i];
    else if (d == D_) x = defe[h];
    u16 hh = f2bf(x);
    hi[i] = hh;
    lo[i] = f2bf(x - bf2f(hh));
}

// ---------- GEMM1: logits = desc @ full_vocab^T, bf16 hi/lo split (3 MFMAs) ----------
// Tile 128(M) x 256(N), BK=32, 512 threads (8 waves, 2x4, 64x64/wave).
// LDS: hi-only double-buffer (48 KB -> 2 blocks/CU). lo via per-lane global.

#define G1_MFMA(a, b, c) __builtin_amdgcn_mfma_f32_16x16x32_bf16((a), (b), (c), 0, 0, 0)

#define G1_STAGE_HI(AhB, BhB, kk) do {                                      \
    GLOAD_LDS16(a_h  + (kk), (char*)(AhB) + tid16);                         \
    GLOAD_LDS16(b_h0 + (kk), (char*)(BhB) + tid16);                         \
    GLOAD_LDS16(b_h1 + (kk), (char*)(BhB) + tid16 + 8192);                  \
} while (0)

// One K-tile:
//  phase 1: issue lo loads (regs), ds_read 8 hi frags, 16 hh MFMA,
//           lgkmcnt(0), barrier
//  phase 2: DMA-stage tile t+2 into this buffer, 32 hl+lh MFMA (compiler
//           inserts the vmcnt for the lo regs; that wait also drains the
//           older DMA of tile t+1), vmcnt(3) formal guarantee, barrier
#define G1_ITER(HA, HB, t) do {                                             \
    bf16x8 afl[4], bfl[4], afh[4], bfh[4];                                  \
    _Pragma("unroll")                                                       \
    for (int i = 0; i < 4; i++) {                                           \
        afl[i] = *(const bf16x8*)(galo + (size_t)i * 16 * H_ + (t) * 32);   \
        bfl[i] = *(const bf16x8*)(gblo + (size_t)i * 16 * H_ + (t) * 32);   \
    }                                                                       \
    _Pragma("unroll")                                                       \
    for (int i = 0; i < 4; i++) {                                           \
        afh[i] = *(const bf16x8*)&HA[aoff[i]];                              \
        bfh[i] = *(const bf16x8*)&HB[boff[i]];                              \
    }                                                                       \
    __builtin_amdgcn_s_setprio(1);                                          \
    _Pragma("unroll")                                                       \
    for (int i = 0; i < 4; i++)                                             \
        _Pragma("unroll")                                                   \
        for (int j = 0; j < 4; j++)                                         \
            acc[i][j] = G1_MFMA(afh[i], bfh[j], acc[i][j]);                 \
    __builtin_amdgcn_s_setprio(0);                                          \
    asm volatile("s_waitcnt lgkmcnt(0)" ::: "memory");                      \
    __builtin_amdgcn_s_barrier();                                           \
    if ((t) + 2 < 32) G1_STAGE_HI(HA, HB, ((t) + 2) * 32);                  \
    __builtin_amdgcn_s_setprio(1);                                          \
    _Pragma("unroll")                                                       \
    for (int i = 0; i < 4; i++)                                             \
        _Pragma("unroll")                                                   \
        for (int j = 0; j < 4; j++) {                                       \
            acc[i][j] = G1_MFMA(afh[i], bfl[j], acc[i][j]);                 \
            acc[i][j] = G1_MFMA(afl[i], bfh[j], acc[i][j]);                 \
        }                                                                   \
    __builtin_amdgcn_s_setprio(0);                                          \
    asm volatile("s_waitcnt vmcnt(3)" ::: "memory");                        \
    __builtin_amdgcn_s_barrier();                                           \
} while (0)

__global__ __launch_bounds__(512, 4)
void gemm1_k(const u16* __restrict__ Ahg, const u16* __restrict__ Alg,
             const u16* __restrict__ Bhg, const u16* __restrict__ Blg,
             float* __restrict__ C) {
    __shared__ u16 Ah0[128 * 32], Bh0[256 * 32];
    __shared__ u16 Ah1[128 * 32], Bh1[256 * 32];

    const int tid  = threadIdx.x;
    const int wave = tid >> 6, lane = tid & 63;
    const int wr = wave >> 2, wc = wave & 3;
    const int quad = lane >> 4, r16 = lane & 15;
    const int m0 = blockIdx.y * 128, n0 = blockIdx.x * 256;

    f32x4 zero = {0.f, 0.f, 0.f, 0.f};
    f32x4 acc[4][4];
#pragma unroll
    for (int i = 0; i < 4; i++)
#pragma unroll
        for (int j = 0; j < 4; j++) acc[i][j] = zero;

    // hi staging: thread t covers row t>>2, chunk t&3 (swizzled source column)
    const int arow = tid >> 2, achk = tid & 3;
    const int ascol = (achk ^ ((arow >> 1) & 3)) * 8;
    const u16* a_h = Ahg + (size_t)(m0 + arow) * H_ + ascol;
    const int brow0 = arow,       bscol0 = (achk ^ ((brow0 >> 1) & 3)) * 8;
    const int brow1 = 128 + arow, bscol1 = (achk ^ ((brow1 >> 1) & 3)) * 8;
    const u16* b_h0 = Bhg + (size_t)(n0 + brow0) * H_ + bscol0;
    const u16* b_h1 = Bhg + (size_t)(n0 + brow1) * H_ + bscol1;
    const int tid16 = tid * 16;

    // lo: per-lane direct global (no swizzle; unique element per lane)
    const u16* galo = Alg + (size_t)(m0 + wr * 64 + r16) * H_ + quad * 8;
    const u16* gblo = Blg + (size_t)(n0 + wc * 64 + r16) * H_ + quad * 8;

    const int aswz = (r16 >> 1) & 3;
    int aoff[4], boff[4];
#pragma unroll
    for (int i = 0; i < 4; i++) {
        aoff[i] = (wr * 64 + i * 16 + r16) * 32 + ((quad ^ aswz) * 8);
        boff[i] = (wc * 64 + i * 16 + r16) * 32 + ((quad ^ aswz) * 8);
    }

    // Prologue: stage tiles 0 and 1; wait only for tile 0 (vmcnt(3)).
    G1_STAGE_HI(Ah0, Bh0, 0);
    G1_STAGE_HI(Ah1, Bh1, 32);
    asm volatile("s_waitcnt vmcnt(3)" ::: "memory");
    __builtin_amdgcn_s_barrier();

    for (int t = 0; t < 32; t += 2) {
        G1_ITER(Ah0, Bh0, t);
        G1_ITER(Ah1, Bh1, t + 1);
    }

    // C/D layout: row = quad*4 + reg, col = lane&15
#pragma unroll
    for (int i = 0; i < 4; i++) {
        int gm = m0 + wr * 64 + i * 16 + quad * 4;
#pragma unroll
        for (int j = 0; j < 4; j++) {
            int gn = n0 + wc * 64 + j * 16 + r16;
            if (gn < DP1) {
#pragma unroll
                for (int reg = 0; reg < 4; reg++)
                    C[(size_t)(gm + reg) * DP1 + gn] = acc[i][j][reg];
            }
        }
    }
}

// ---------- fused softmax + sparse gather epilogue (register-resident) ----------
// One block per (b,l) row. Thread t holds elements {s*1024 + t*4 + e}.
// concept[row] = p[D_]*desc[row] + sum_{d: e_d > 1e-7*Z} p_d * vocab[d].
// Dropped mass <= 1e-3 worst case; typically ~e^-16 (logits ~ N(0,32^2)).
__global__ __launch_bounds__(256)
void softmax_gather_k(float* __restrict__ sim, const float* __restrict__ vocab,
                      const float* __restrict__ desc, float* __restrict__ out) {
    __shared__ float red[8];
    __shared__ float wslot;
    __shared__ int   cnt;
    __shared__ int   cidx[CANDS];
    __shared__ float cp[CANDS];
    const int tid = threadIdx.x;
    const int row = blockIdx.x;
    float* rowp = sim + (size_t)row * DP1;
    if (tid == 0) cnt = 0;

    f32x4 v[10];
#pragma unroll
    for (int s = 0; s < 9; s++) v[s] = *(const f32x4*)(rowp + s * 1024 + tid * 4);
    {
        const int base = 9216 + tid * 4;
#pragma unroll
        for (int e = 0; e < 4; e++)
            v[9][e] = (base + e <= D_) ? rowp[base + e] : -3.4e38f;
    }

    float mx = -3.4e38f;
#pragma unroll
    for (int s = 0; s < 10; s++)
        mx = fmaxf(mx, fmaxf(fmaxf(v[s][0], v[s][1]), fmaxf(v[s][2], v[s][3])));
#pragma unroll
    for (int off = 32; off; off >>= 1) mx = fmaxf(mx, __shfl_down(mx, off, 64));
    if ((tid & 63) == 0) red[tid >> 6] = mx;
    __syncthreads();
    mx = fmaxf(fmaxf(red[0], red[1]), fmaxf(red[2], red[3]));

    float s0 = 0.f;
#pragma unroll
    for (int s = 0; s < 10; s++)
#pragma unroll
        for (int e = 0; e < 4; e++) {
            float ex = __expf(v[s][e] - mx);
            v[s][e] = ex;                      // exp(-huge)=0 for pad lanes
            s0 += ex;
        }
#pragma unroll
    for (int off = 32; off; off >>= 1) s0 += __shfl_down(s0, off, 64);
    __syncthreads();                            // red[] reuse hazard
    if ((tid & 63) == 0) red[tid >> 6] = s0;
    __syncthreads();
    const float sum = red[0] + red[1] + red[2] + red[3];
    const float inv = 1.f / sum;
    const float thr = sum * 1e-7f;

    // write normalized probs + collect candidates (concept slots d < D_)
#pragma unroll
    for (int s = 0; s < 9; s++) {
        f32x4 p = v[s] * inv;
        *(f32x4*)(rowp + s * 1024 + tid * 4) = p;
#pragma unroll
        for (int e = 0; e < 4; e++)
            if (v[s][e] > thr) {
                int k = atomicAdd(&cnt, 1);
                if (k < CANDS) { cidx[k] = s * 1024 + tid * 4 + e; cp[k] = p[e]; }
            }
    }
    {
        const int base = 9216 + tid * 4;
#pragma unroll
        for (int e = 0; e < 4; e++) {
            int idx = base + e;
            if (idx <= D_) {
                float p = v[9][e] * inv;
                rowp[idx] = p;
                if (idx == D_) wslot = p;
                else if (v[9][e] > thr) {
                    int k = atomicAdd(&cnt, 1);
                    if (k < CANDS) { cidx[k] = idx; cp[k] = p; }
                }
            }
        }
    }
    __syncthreads();

    const float w = wslot;
    f32x4 a = w * ((const f32x4*)(desc + (size_t)row * H_))[tid];
    if (cnt <= CANDS) {
        const int k = cnt;
        for (int c = 0; c < k; c++)
            a += cp[c] * ((const f32x4*)(vocab + (size_t)cidx[c] * H_))[tid];
    } else {
        // overflow fallback (pathological rows only): scan normalized probs
        const float pthr = thr * inv;
        for (int d = 0; d < D_; d++) {
            float p = rowp[d];
            if (p > pthr) a += p * ((const f32x4*)(vocab + (size_t)d * H_))[tid];
        }
    }
    ((f32x4*)(out + (size_t)row * H_))[tid] = a;
}

// ---------- fallback (ws too small): exact fp32 logits, slow but correct ----------
__global__ __launch_bounds__(256)
void naive_logits_k(const float* __restrict__ vocab, const float* __restrict__ desc,
                    const float* __restrict__ defe, float* __restrict__ sim) {
    int d = blockIdx.x * 256 + threadIdx.x;
    if (d >= DP1) return;
    const float* vr = (d < D_) ? (vocab + (size_t)d * H_) : defe;
    const float* dr = desc + (size_t)blockIdx.y * H_;
    float s = 0.f;
    for (int h = 0; h < H_; h++) s = fmaf(dr[h], vr[h], s);
    sim[(size_t)blockIdx.y * DP1 + d] = s;
}

extern "C" void kernel_launch(void* const* d_in, const int* in_sizes, int n_in,
                              void* d_out, int out_size, void* d_ws, size_t ws_size,
                              hipStream_t stream) {
    (void)in_sizes; (void)n_in; (void)out_size;
    const float* vocab = (const float*)d_in[0];
    const float* desc  = (const float*)d_in[1];
    const float* defe  = (const float*)d_in[2];
    float* out = (float*)d_out;                          // concept: [4096][1024]
    float* sim = out + (size_t)BL * H_;                  // sim:     [4096][10001]

    // ws layout (bytes):
    //   desc_hi @ 0          (8,388,608)
    //   desc_lo @ 8,388,608  (8,388,608)
    //   fv_hi   @ 16,777,216 (20,971,520 = NPAD2*H_*2)
    //   fv_lo   @ 37,748,736 (20,971,520)          -> REQ1 = 58,720,256
    const size_t REQ1 = 58720256ull;
    char* ws = (char*)d_ws;

    if (ws_size >= REQ1) {
        u16* dhi = (u16*)(ws + 0);
        u16* dlo = (u16*)(ws + 8388608);
        u16* fhi = (u16*)(ws + 16777216);
        u16* flo = (u16*)(ws + 37748736);

        split_desc_k<<<16384, 256, 0, stream>>>(desc, dhi, dlo);
        split_fv_k<<<40960, 256, 0, stream>>>(vocab, defe, fhi, flo);
        gemm1_k<<<dim3(40, 32), 512, 0, stream>>>(dhi, dlo, fhi, flo, sim);
    } else {
        naive_logits_k<<<dim3(40, BL), 256, 0, stream>>>(vocab, desc, defe, sim);
    }
    softmax_gather_k<<<4096, 256, 0, stream>>>(sim, vocab, desc, out);
}

// Round 5
// 1994.175 us; speedup vs baseline: 1.0298x; 1.0298x over previous
//
#include <hip/hip_runtime.h>
#include <stdint.h>

#define D_    10000
#define DP1   10001
#define NPAD2 10240      // 40 * 256 (padded vocab rows for GEMM1, N-tile 256)
#define H_    1024
#define BL    4096       // B * L
#define CANDS 1024       // candidate list capacity (p > 1e-7 of mass; typ. 2-6)

typedef float  f32x4  __attribute__((ext_vector_type(4)));
typedef __bf16 bf16x8 __attribute__((ext_vector_type(8)));
typedef unsigned short u16;
typedef u16    u16x8  __attribute__((ext_vector_type(8)));

// ---------- bf16 helpers (round-to-nearest-even) ----------
__device__ __forceinline__ u16 f2bf(float x) {
    union { float f; unsigned u; } v; v.f = x;
    unsigned r = v.u + 0x7FFFu + ((v.u >> 16) & 1u);
    return (u16)(r >> 16);
}
__device__ __forceinline__ float bf2f(u16 b) {
    union { float f; unsigned u; } v; v.u = ((unsigned)b) << 16;
    return v.f;
}

// async global -> LDS, 16B per lane (HW: wave-uniform base + lane*16)
#define GLOAD_LDS16(gsrc, ldst)                                             \
    __builtin_amdgcn_global_load_lds(                                       \
        (__attribute__((address_space(1))) void*)(void*)(gsrc),             \
        (__attribute__((address_space(3))) void*)(void*)(ldst), 16, 0, 0)

// History:
// R3: LDS chunk swizzle -> SQ_LDS_BANK_CONFLICT 2.07e7 -> 0.
// R6: 2-deep prefetch + counted vmcnt: occupancy 35->22%, dur flat (248us).
// R7: 256^2 tile + 4-phase: REGRESSED (268us). Reverted.
// R8: sparse-gather epilogue replaced gemm2 pipeline: 692->648us, absmax
//   0.0313->0.0156.
// R9: per-lane global lo fragments: DISASTER (1800us). FETCH 178MB->3.4GB:
//   stride-2048B lane pattern = 1 cache line per 16B fragment, 4x wave
//   re-read. Lesson: operand fragments MUST come from LDS (coalesced DMA
//   staging); only the LDS *capacity* may be traded. Useful signal: with
//   __launch_bounds__(512,4) compiler fit VGPR=64 (+64 AGPR = 128 unified)
//   holding 16 live frags -> 4 waves/SIMD register budget is feasible.
// R10 (this): gemm1 latency/barrier-bound at 1 block/CU (real MFMA-pipe
//   busy ~12.5% from raw arithmetic; MfmaUtil 46% is a derived-counter
//   artifact). Fix: hi dbuf (48KB) + lo SINGLE buffer (24KB) = 72KB ->
//   2 blocks/CU (16 waves, 4/SIMD) so barrier stalls of one block are
//   covered by the other. lo(t+1) staged in P2 after the P1 barrier that
//   guarantees all waves finished reading lo(t); vmcnt(3) drains it.

// ---------- prep: split fp32 -> bf16 hi + lo ----------
__global__ __launch_bounds__(256)
void split_desc_k(const float* __restrict__ desc, u16* __restrict__ hi, u16* __restrict__ lo) {
    size_t i = (size_t)blockIdx.x * 256 + threadIdx.x;   // exactly BL*H_
    float x = desc[i];
    u16 h = f2bf(x);
    hi[i] = h;
    lo[i] = f2bf(x - bf2f(h));
}

__global__ __launch_bounds__(256)
void split_fv_k(const float* __restrict__ vocab, const float* __restrict__ defe,
                u16* __restrict__ hi, u16* __restrict__ lo) {
    size_t i = (size_t)blockIdx.x * 256 + threadIdx.x;   // exactly NPAD2*H_
    int d = (int)(i >> 10);
    int h = (int)(i & 1023);
    float x = 0.f;
    if (d < D_)       x = vocab[i];
    else if (d == D_) x = defe[h];
    u16 hh = f2bf(x);
    hi[i] = hh;
    lo[i] = f2bf(x - bf2f(hh));
}

// ---------- GEMM1: logits = desc @ full_vocab^T, bf16 hi/lo split (3 MFMAs) ----------
// Tile 128(M) x 256(N), BK=32, 512 threads (8 waves, 2x4, 64x64/wave).
// LDS 72KB: hi double-buffered (48KB) + lo single-buffered (24KB) -> 2 blocks/CU.

#define G1_MFMA(a, b, c) __builtin_amdgcn_mfma_f32_16x16x32_bf16((a), (b), (c), 0, 0, 0)

#define G1_STAGE_HI(HA, HB, kk) do {                                        \
    GLOAD_LDS16(a_h  + (kk), (char*)(HA) + tid16);                          \
    GLOAD_LDS16(b_h0 + (kk), (char*)(HB) + tid16);                          \
    GLOAD_LDS16(b_h1 + (kk), (char*)(HB) + tid16 + 8192);                   \
} while (0)

#define G1_STAGE_LO(kk) do {                                                \
    GLOAD_LDS16(a_l  + (kk), (char*)Al + tid16);                            \
    GLOAD_LDS16(b_l0 + (kk), (char*)Bl + tid16);                            \
    GLOAD_LDS16(b_l1 + (kk), (char*)Bl + tid16 + 8192);                     \
} while (0)

// One K-tile:
//  P1: ds_read 16 frags (hi from H[t&1], lo from L); 16 hh MFMA;
//      lgkmcnt(0); barrier  (all waves done reading L and H[t&1])
//  P2: stage lo(t+1)->L FIRST, then hi(t+2)->H[t&1]; 32 hl+lh MFMA;
//      vmcnt(3) drains hi(t+1)+lo(t+1), leaves hi(t+2) in flight; barrier.
//  Invariant at P2 entry: outstanding = hi(t+1)'s 3 loads.
#define G1_ITER(HA, HB, t) do {                                             \
    bf16x8 afh[4], afl[4], bfh[4], bfl[4];                                  \
    _Pragma("unroll")                                                       \
    for (int i = 0; i < 4; i++) {                                           \
        afh[i] = *(const bf16x8*)&HA[aoff[i]];                              \
        bfh[i] = *(const bf16x8*)&HB[boff[i]];                              \
        afl[i] = *(const bf16x8*)&Al[aoff[i]];                              \
        bfl[i] = *(const bf16x8*)&Bl[boff[i]];                              \
    }                                                                       \
    __builtin_amdgcn_s_setprio(1);                                          \
    _Pragma("unroll")                                                       \
    for (int i = 0; i < 4; i++)                                             \
        _Pragma("unroll")                                                   \
        for (int j = 0; j < 4; j++)                                         \
            acc[i][j] = G1_MFMA(afh[i], bfh[j], acc[i][j]);                 \
    __builtin_amdgcn_s_setprio(0);                                          \
    asm volatile("s_waitcnt lgkmcnt(0)" ::: "memory");                      \
    __builtin_amdgcn_s_barrier();                                           \
    if ((t) + 1 < 32) G1_STAGE_LO(((t) + 1) * 32);                          \
    if ((t) + 2 < 32) G1_STAGE_HI(HA, HB, ((t) + 2) * 32);                  \
    __builtin_amdgcn_s_setprio(1);                                          \
    _Pragma("unroll")                                                       \
    for (int i = 0; i < 4; i++)                                             \
        _Pragma("unroll")                                                   \
        for (int j = 0; j < 4; j++) {                                       \
            acc[i][j] = G1_MFMA(afh[i], bfl[j], acc[i][j]);                 \
            acc[i][j] = G1_MFMA(afl[i], bfh[j], acc[i][j]);                 \
        }                                                                   \
    __builtin_amdgcn_s_setprio(0);                                          \
    if ((t) + 2 < 32)      asm volatile("s_waitcnt vmcnt(3)" ::: "memory"); \
    else if ((t) + 1 < 32) asm volatile("s_waitcnt vmcnt(0)" ::: "memory"); \
    __builtin_amdgcn_s_barrier();                                           \
} while (0)

__global__ __launch_bounds__(512, 4)
void gemm1_k(const u16* __restrict__ Ahg, const u16* __restrict__ Alg,
             const u16* __restrict__ Bhg, const u16* __restrict__ Blg,
             float* __restrict__ C) {
    __shared__ u16 Ah0[128 * 32], Bh0[256 * 32];    // hi double buffer
    __shared__ u16 Ah1[128 * 32], Bh1[256 * 32];
    __shared__ u16 Al[128 * 32],  Bl[256 * 32];     // lo single buffer

    const int tid  = threadIdx.x;
    const int wave = tid >> 6, lane = tid & 63;
    const int wr = wave >> 2, wc = wave & 3;
    const int quad = lane >> 4, r16 = lane & 15;
    const int m0 = blockIdx.y * 128, n0 = blockIdx.x * 256;

    f32x4 zero = {0.f, 0.f, 0.f, 0.f};
    f32x4 acc[4][4];
#pragma unroll
    for (int i = 0; i < 4; i++)
#pragma unroll
        for (int j = 0; j < 4; j++) acc[i][j] = zero;

    // staging: thread t covers row t>>2, chunk t&3 (swizzled source column)
    const int arow = tid >> 2, achk = tid & 3;
    const int ascol = (achk ^ ((arow >> 1) & 3)) * 8;
    const u16* a_h = Ahg + (size_t)(m0 + arow) * H_ + ascol;
    const u16* a_l = Alg + (size_t)(m0 + arow) * H_ + ascol;
    const int brow0 = arow,       bscol0 = (achk ^ ((brow0 >> 1) & 3)) * 8;
    const int brow1 = 128 + arow, bscol1 = (achk ^ ((brow1 >> 1) & 3)) * 8;
    const u16* b_h0 = Bhg + (size_t)(n0 + brow0) * H_ + bscol0;
    const u16* b_h1 = Bhg + (size_t)(n0 + brow1) * H_ + bscol1;
    const u16* b_l0 = Blg + (size_t)(n0 + brow0) * H_ + bscol0;
    const u16* b_l1 = Blg + (size_t)(n0 + brow1) * H_ + bscol1;
    const int tid16 = tid * 16;

    const int aswz = (r16 >> 1) & 3;
    int aoff[4], boff[4];
#pragma unroll
    for (int i = 0; i < 4; i++) {
        aoff[i] = (wr * 64 + i * 16 + r16) * 32 + ((quad ^ aswz) * 8);
        boff[i] = (wc * 64 + i * 16 + r16) * 32 + ((quad ^ aswz) * 8);
    }

    // Prologue: issue hi(0), lo(0), hi(1); vmcnt(3) leaves hi(1) in flight.
    G1_STAGE_HI(Ah0, Bh0, 0);
    G1_STAGE_LO(0);
    G1_STAGE_HI(Ah1, Bh1, 32);
    asm volatile("s_waitcnt vmcnt(3)" ::: "memory");
    __builtin_amdgcn_s_barrier();

    for (int t = 0; t < 32; t += 2) {
        G1_ITER(Ah0, Bh0, t);
        G1_ITER(Ah1, Bh1, t + 1);
    }

    // C/D layout: row = quad*4 + reg, col = lane&15
#pragma unroll
    for (int i = 0; i < 4; i++) {
        int gm = m0 + wr * 64 + i * 16 + quad * 4;
#pragma unroll
        for (int j = 0; j < 4; j++) {
            int gn = n0 + wc * 64 + j * 16 + r16;
            if (gn < DP1) {
#pragma unroll
                for (int reg = 0; reg < 4; reg++)
                    C[(size_t)(gm + reg) * DP1 + gn] = acc[i][j][reg];
            }
        }
    }
}

// ---------- fused softmax + sparse gather epilogue (register-resident) ----------
// One block per (b,l) row. Thread t holds elements {s*1024 + t*4 + e}.
// concept[row] = p[D_]*desc[row] + sum_{d: e_d > 1e-7*Z} p_d * vocab[d].
// Dropped mass <= 1e-3 worst case; typically ~e^-16 (logits ~ N(0,32^2)).
__global__ __launch_bounds__(256)
void softmax_gather_k(float* __restrict__ sim, const float* __restrict__ vocab,
                      const float* __restrict__ desc, float* __restrict__ out) {
    __shared__ float red[8];
    __shared__ float wslot;
    __shared__ int   cnt;
    __shared__ int   cidx[CANDS];
    __shared__ float cp[CANDS];
    const int tid = threadIdx.x;
    const int row = blockIdx.x;
    float* rowp = sim + (size_t)row * DP1;
    if (tid == 0) cnt = 0;

    f32x4 v[10];
#pragma unroll
    for (int s = 0; s < 9; s++) v[s] = *(const f32x4*)(rowp + s * 1024 + tid * 4);
    {
        const int base = 9216 + tid * 4;
#pragma unroll
        for (int e = 0; e < 4; e++)
            v[9][e] = (base + e <= D_) ? rowp[base + e] : -3.4e38f;
    }

    float mx = -3.4e38f;
#pragma unroll
    for (int s = 0; s < 10; s++)
        mx = fmaxf(mx, fmaxf(fmaxf(v[s][0], v[s][1]), fmaxf(v[s][2], v[s][3])));
#pragma unroll
    for (int off = 32; off; off >>= 1) mx = fmaxf(mx, __shfl_down(mx, off, 64));
    if ((tid & 63) == 0) red[tid >> 6] = mx;
    __syncthreads();
    mx = fmaxf(fmaxf(red[0], red[1]), fmaxf(red[2], red[3]));

    float s0 = 0.f;
#pragma unroll
    for (int s = 0; s < 10; s++)
#pragma unroll
        for (int e = 0; e < 4; e++) {
            float ex = __expf(v[s][e] - mx);
            v[s][e] = ex;                      // exp(-huge)=0 for pad lanes
            s0 += ex;
        }
#pragma unroll
    for (int off = 32; off; off >>= 1) s0 += __shfl_down(s0, off, 64);
    __syncthreads();                            // red[] reuse hazard
    if ((tid & 63) == 0) red[tid >> 6] = s0;
    __syncthreads();
    const float sum = red[0] + red[1] + red[2] + red[3];
    const float inv = 1.f / sum;
    const float thr = sum * 1e-7f;

    // write normalized probs + collect candidates (concept slots d < D_)
#pragma unroll
    for (int s = 0; s < 9; s++) {
        f32x4 p = v[s] * inv;
        *(f32x4*)(rowp + s * 1024 + tid * 4) = p;
#pragma unroll
        for (int e = 0; e < 4; e++)
            if (v[s][e] > thr) {
                int k = atomicAdd(&cnt, 1);
                if (k < CANDS) { cidx[k] = s * 1024 + tid * 4 + e; cp[k] = p[e]; }
            }
    }
    {
        const int base = 9216 + tid * 4;
#pragma unroll
        for (int e = 0; e < 4; e++) {
            int idx = base + e;
            if (idx <= D_) {
                float p = v[9][e] * inv;
                rowp[idx] = p;
                if (idx == D_) wslot = p;
                else if (v[9][e] > thr) {
                    int k = atomicAdd(&cnt, 1);
                    if (k < CANDS) { cidx[k] = idx; cp[k] = p; }
                }
            }
        }
    }
    __syncthreads();

    const float w = wslot;
    f32x4 a = w * ((const f32x4*)(desc + (size_t)row * H_))[tid];
    if (cnt <= CANDS) {
        const int k = cnt;
        for (int c = 0; c < k; c++)
            a += cp[c] * ((const f32x4*)(vocab + (size_t)cidx[c] * H_))[tid];
    } else {
        // overflow fallback (pathological rows only): scan normalized probs
        const float pthr = thr * inv;
        for (int d = 0; d < D_; d++) {
            float p = rowp[d];
            if (p > pthr) a += p * ((const f32x4*)(vocab + (size_t)d * H_))[tid];
        }
    }
    ((f32x4*)(out + (size_t)row * H_))[tid] = a;
}

// ---------- fallback (ws too small): exact fp32 logits, slow but correct ----------
__global__ __launch_bounds__(256)
void naive_logits_k(const float* __restrict__ vocab, const float* __restrict__ desc,
                    const float* __restrict__ defe, float* __restrict__ sim) {
    int d = blockIdx.x * 256 + threadIdx.x;
    if (d >= DP1) return;
    const float* vr = (d < D_) ? (vocab + (size_t)d * H_) : defe;
    const float* dr = desc + (size_t)blockIdx.y * H_;
    float s = 0.f;
    for (int h = 0; h < H_; h++) s = fmaf(dr[h], vr[h], s);
    sim[(size_t)blockIdx.y * DP1 + d] = s;
}

extern "C" void kernel_launch(void* const* d_in, const int* in_sizes, int n_in,
                              void* d_out, int out_size, void* d_ws, size_t ws_size,
                              hipStream_t stream) {
    (void)in_sizes; (void)n_in; (void)out_size;
    const float* vocab = (const float*)d_in[0];
    const float* desc  = (const float*)d_in[1];
    const float* defe  = (const float*)d_in[2];
    float* out = (float*)d_out;                          // concept: [4096][1024]
    float* sim = out + (size_t)BL * H_;                  // sim:     [4096][10001]

    // ws layout (bytes):
    //   desc_hi @ 0          (8,388,608)
    //   desc_lo @ 8,388,608  (8,388,608)
    //   fv_hi   @ 16,777,216 (20,971,520 = NPAD2*H_*2)
    //   fv_lo   @ 37,748,736 (20,971,520)          -> REQ1 = 58,720,256
    const size_t REQ1 = 58720256ull;
    char* ws = (char*)d_ws;

    if (ws_size >= REQ1) {
        u16* dhi = (u16*)(ws + 0);
        u16* dlo = (u16*)(ws + 8388608);
        u16* fhi = (u16*)(ws + 16777216);
        u16* flo = (u16*)(ws + 37748736);

        split_desc_k<<<16384, 256, 0, stream>>>(desc, dhi, dlo);
        split_fv_k<<<40960, 256, 0, stream>>>(vocab, defe, fhi, flo);
        gemm1_k<<<dim3(40, 32), 512, 0, stream>>>(dhi, dlo, fhi, flo, sim);
    } else {
        naive_logits_k<<<dim3(40, BL), 256, 0, stream>>>(vocab, desc, defe, sim);
    }
    softmax_gather_k<<<4096, 256, 0, stream>>>(sim, vocab, desc, out);
}

// Round 6
// 517.123 us; speedup vs baseline: 3.9713x; 3.8563x over previous
//
#include <hip/hip_runtime.h>
#include <stdint.h>

#define D_    10000
#define DP1   10001
#define NPAD2 10240      // 40 * 256 (padded vocab rows for GEMM1, N-tile 256)
#define H_    1024
#define BL    4096       // B * L
#define CANDS 1024       // candidate list capacity (p > 1e-7 of mass; typ. 2-6)

typedef float  f32x4  __attribute__((ext_vector_type(4)));
typedef __bf16 bf16x8 __attribute__((ext_vector_type(8)));
typedef unsigned short u16;
typedef u16    u16x8  __attribute__((ext_vector_type(8)));

// ---------- bf16 helpers (round-to-nearest-even) ----------
__device__ __forceinline__ u16 f2bf(float x) {
    union { float f; unsigned u; } v; v.f = x;
    unsigned r = v.u + 0x7FFFu + ((v.u >> 16) & 1u);
    return (u16)(r >> 16);
}
__device__ __forceinline__ float bf2f(u16 b) {
    union { float f; unsigned u; } v; v.u = ((unsigned)b) << 16;
    return v.f;
}

// async global -> LDS, 16B per lane (HW: wave-uniform base + lane*16)
#define GLOAD_LDS16(gsrc, ldst)                                             \
    __builtin_amdgcn_global_load_lds(                                       \
        (__attribute__((address_space(1))) void*)(void*)(gsrc),             \
        (__attribute__((address_space(3))) void*)(void*)(ldst), 16, 0, 0)

// History:
// R3: LDS chunk swizzle -> SQ_LDS_BANK_CONFLICT 2.07e7 -> 0.
// R6: 2-deep prefetch + counted vmcnt, (512,2), 96KB: 248-250us (PROVEN,
//   3 benches). MfmaUtil 46% is a derived-counter artifact; real MFMA-pipe
//   busy ~12.5%, latency/barrier-bound at ~1.5 blocks/CU.
// R7: 256^2 tile + 4-phase: REGRESSED (268us). Reverted.
// R8: sparse-gather epilogue replaced gemm2 pipeline: 692->648us, absmax
//   0.0313->0.0156. Register-resident gather (R9+) worth ~130us vs LDS form
//   (total-gemm1: 400us -> 254-270us).
// R9/R10: BOTH disasters were SCRATCH SPILL, not (only) coalescing:
//   WRITE_SIZE 4.8GB >> 164MB C output = spill signature. (512,4) caps
//   unified regs at 128/thread; schedule needs acc64+frags64+addr~28=156.
//   LESSON: check WRITE_SIZE vs output size FIRST; 16-live-frag K-step
//   cannot run at 4 waves/SIMD. 2 blocks/CU via LDS shrink is a dead end
//   for THIS schedule (register-limited, not LDS-limited).
// R11 (this): consolidate the two proven bests: R6 gemm1 (exact) +
//   register softmax_gather. Expected total ~505-530us.

// ---------- prep: split fp32 -> bf16 hi + lo ----------
__global__ __launch_bounds__(256)
void split_desc_k(const float* __restrict__ desc, u16* __restrict__ hi, u16* __restrict__ lo) {
    size_t i = (size_t)blockIdx.x * 256 + threadIdx.x;   // exactly BL*H_
    float x = desc[i];
    u16 h = f2bf(x);
    hi[i] = h;
    lo[i] = f2bf(x - bf2f(h));
}

__global__ __launch_bounds__(256)
void split_fv_k(const float* __restrict__ vocab, const float* __restrict__ defe,
                u16* __restrict__ hi, u16* __restrict__ lo) {
    size_t i = (size_t)blockIdx.x * 256 + threadIdx.x;   // exactly NPAD2*H_
    int d = (int)(i >> 10);
    int h = (int)(i & 1023);
    float x = 0.f;
    if (d < D_)       x = vocab[i];
    else if (d == D_) x = defe[h];
    u16 hh = f2bf(x);
    hi[i] = hh;
    lo[i] = f2bf(x - bf2f(hh));
}

// ---------- GEMM1: logits = desc @ full_vocab^T, bf16 hi/lo split (3 MFMAs) ----------
// Tile 128(M) x 256(N), BK=32, 512 threads (8 waves, wave grid 2x4, 64x64/wave).
// Double-buffered LDS (96 KB), 2-deep prefetch with counted vmcnt.  [R6 form]

#define G1_MFMA(a, b, c) __builtin_amdgcn_mfma_f32_16x16x32_bf16((a), (b), (c), 0, 0, 0)

#define G1_STAGE(AhB, AlB, BhB, BlB, kk) do {                               \
    GLOAD_LDS16(a_h  + (kk), (char*)(AhB) + tid16);                         \
    GLOAD_LDS16(a_l  + (kk), (char*)(AlB) + tid16);                         \
    GLOAD_LDS16(b_h0 + (kk), (char*)(BhB) + tid16);                         \
    GLOAD_LDS16(b_h1 + (kk), (char*)(BhB) + tid16 + 8192);                  \
    GLOAD_LDS16(b_l0 + (kk), (char*)(BlB) + tid16);                         \
    GLOAD_LDS16(b_l1 + (kk), (char*)(BlB) + tid16 + 8192);                  \
} while (0)

// One K-tile: phase 0 = {ds_read 16 frags, 24 MFMA (i=0,1), lgkmcnt(0), barrier}
//             phase 1 = {STAGE t+2 -> this buffer, 24 MFMA (i=2,3), vmcnt(6), barrier}
// vmcnt(6): tile t+1's 6 loads (oldest) complete; tile t+2's 6 stay in flight.
#define G1_ITER(AhB, AlB, BhB, BlB, t) do {                                 \
    bf16x8 afh[4], afl[4], bfh[4], bfl[4];                                  \
    _Pragma("unroll")                                                       \
    for (int i = 0; i < 4; i++) {                                           \
        afh[i] = *(const bf16x8*)&AhB[aoff[i]];                             \
        afl[i] = *(const bf16x8*)&AlB[aoff[i]];                             \
        bfh[i] = *(const bf16x8*)&BhB[boff[i]];                             \
        bfl[i] = *(const bf16x8*)&BlB[boff[i]];                             \
    }                                                                       \
    __builtin_amdgcn_s_setprio(1);                                          \
    _Pragma("unroll")                                                       \
    for (int i = 0; i < 2; i++)                                             \
        _Pragma("unroll")                                                   \
        for (int j = 0; j < 4; j++) {                                       \
            acc[i][j] = G1_MFMA(afh[i], bfh[j], acc[i][j]);                 \
            acc[i][j] = G1_MFMA(afh[i], bfl[j], acc[i][j]);                 \
            acc[i][j] = G1_MFMA(afl[i], bfh[j], acc[i][j]);                 \
        }                                                                   \
    __builtin_amdgcn_s_setprio(0);                                          \
    asm volatile("s_waitcnt lgkmcnt(0)" ::: "memory");                      \
    __builtin_amdgcn_s_barrier();                                           \
    if ((t) + 2 < 32) G1_STAGE(AhB, AlB, BhB, BlB, ((t) + 2) * 32);         \
    __builtin_amdgcn_s_setprio(1);                                          \
    _Pragma("unroll")                                                       \
    for (int i = 2; i < 4; i++)                                             \
        _Pragma("unroll")                                                   \
        for (int j = 0; j < 4; j++) {                                       \
            acc[i][j] = G1_MFMA(afh[i], bfh[j], acc[i][j]);                 \
            acc[i][j] = G1_MFMA(afh[i], bfl[j], acc[i][j]);                 \
            acc[i][j] = G1_MFMA(afl[i], bfh[j], acc[i][j]);                 \
        }                                                                   \
    __builtin_amdgcn_s_setprio(0);                                          \
    if ((t) + 2 < 32)      asm volatile("s_waitcnt vmcnt(6)" ::: "memory"); \
    else if ((t) + 1 < 32) asm volatile("s_waitcnt vmcnt(0)" ::: "memory"); \
    __builtin_amdgcn_s_barrier();                                           \
} while (0)

__global__ __launch_bounds__(512, 2)
void gemm1_k(const u16* __restrict__ Ahg, const u16* __restrict__ Alg,
             const u16* __restrict__ Bhg, const u16* __restrict__ Blg,
             float* __restrict__ C) {
    // Two buffers as SEPARATE objects so the LDS-DMA waitcnt pass can
    // disambiguate: DMA into buf1 never forces a wait before ds_read of buf0.
    __shared__ u16 Ah0[128 * 32], Al0[128 * 32], Bh0[256 * 32], Bl0[256 * 32];
    __shared__ u16 Ah1[128 * 32], Al1[128 * 32], Bh1[256 * 32], Bl1[256 * 32];

    const int tid  = threadIdx.x;
    const int wave = tid >> 6, lane = tid & 63;
    const int wr = wave >> 2, wc = wave & 3;
    const int quad = lane >> 4, r16 = lane & 15;
    const int m0 = blockIdx.y * 128, n0 = blockIdx.x * 256;

    f32x4 zero = {0.f, 0.f, 0.f, 0.f};
    f32x4 acc[4][4];
#pragma unroll
    for (int i = 0; i < 4; i++)
#pragma unroll
        for (int j = 0; j < 4; j++) acc[i][j] = zero;

    // staging: thread t covers row t>>2, chunk t&3 (swizzled source column)
    const int arow = tid >> 2, achk = tid & 3;
    const int ascol = (achk ^ ((arow >> 1) & 3)) * 8;
    const u16* a_h = Ahg + (size_t)(m0 + arow) * H_ + ascol;
    const u16* a_l = Alg + (size_t)(m0 + arow) * H_ + ascol;
    const int brow0 = arow,        bscol0 = (achk ^ ((brow0 >> 1) & 3)) * 8;
    const int brow1 = 128 + arow,  bscol1 = (achk ^ ((brow1 >> 1) & 3)) * 8;
    const u16* b_h0 = Bhg + (size_t)(n0 + brow0) * H_ + bscol0;
    const u16* b_h1 = Bhg + (size_t)(n0 + brow1) * H_ + bscol1;
    const u16* b_l0 = Blg + (size_t)(n0 + brow0) * H_ + bscol0;
    const u16* b_l1 = Blg + (size_t)(n0 + brow1) * H_ + bscol1;
    const int tid16 = tid * 16;
    const int aswz = (r16 >> 1) & 3;

    // fragment LDS element offsets (same for both buffers)
    int aoff[4], boff[4];
#pragma unroll
    for (int i = 0; i < 4; i++) {
        aoff[i] = (wr * 64 + i * 16 + r16) * 32 + ((quad ^ aswz) * 8);
        boff[i] = (wc * 64 + i * 16 + r16) * 32 + ((quad ^ aswz) * 8);
    }

    // Prologue: stage tiles 0 and 1; wait only for tile 0 (vmcnt(6)).
    G1_STAGE(Ah0, Al0, Bh0, Bl0, 0);
    G1_STAGE(Ah1, Al1, Bh1, Bl1, 32);
    asm volatile("s_waitcnt vmcnt(6)" ::: "memory");
    __builtin_amdgcn_s_barrier();

    for (int t = 0; t < 32; t += 2) {
        G1_ITER(Ah0, Al0, Bh0, Bl0, t);
        G1_ITER(Ah1, Al1, Bh1, Bl1, t + 1);
    }

    // C/D layout: row = quad*4 + reg, col = lane&15
#pragma unroll
    for (int i = 0; i < 4; i++) {
        int gm = m0 + wr * 64 + i * 16 + quad * 4;
#pragma unroll
        for (int j = 0; j < 4; j++) {
            int gn = n0 + wc * 64 + j * 16 + r16;
            if (gn < DP1) {
#pragma unroll
                for (int reg = 0; reg < 4; reg++)
                    C[(size_t)(gm + reg) * DP1 + gn] = acc[i][j][reg];
            }
        }
    }
}

// ---------- fused softmax + sparse gather epilogue (register-resident) ----------
// One block per (b,l) row. Thread t holds elements {s*1024 + t*4 + e}.
// concept[row] = p[D_]*desc[row] + sum_{d: e_d > 1e-7*Z} p_d * vocab[d].
// Dropped mass <= 1e-3 worst case; typically ~e^-16 (logits ~ N(0,32^2)).
__global__ __launch_bounds__(256)
void softmax_gather_k(float* __restrict__ sim, const float* __restrict__ vocab,
                      const float* __restrict__ desc, float* __restrict__ out) {
    __shared__ float red[8];
    __shared__ float wslot;
    __shared__ int   cnt;
    __shared__ int   cidx[CANDS];
    __shared__ float cp[CANDS];
    const int tid = threadIdx.x;
    const int row = blockIdx.x;
    float* rowp = sim + (size_t)row * DP1;
    if (tid == 0) cnt = 0;

    f32x4 v[10];
#pragma unroll
    for (int s = 0; s < 9; s++) v[s] = *(const f32x4*)(rowp + s * 1024 + tid * 4);
    {
        const int base = 9216 + tid * 4;
#pragma unroll
        for (int e = 0; e < 4; e++)
            v[9][e] = (base + e <= D_) ? rowp[base + e] : -3.4e38f;
    }

    float mx = -3.4e38f;
#pragma unroll
    for (int s = 0; s < 10; s++)
        mx = fmaxf(mx, fmaxf(fmaxf(v[s][0], v[s][1]), fmaxf(v[s][2], v[s][3])));
#pragma unroll
    for (int off = 32; off; off >>= 1) mx = fmaxf(mx, __shfl_down(mx, off, 64));
    if ((tid & 63) == 0) red[tid >> 6] = mx;
    __syncthreads();
    mx = fmaxf(fmaxf(red[0], red[1]), fmaxf(red[2], red[3]));

    float s0 = 0.f;
#pragma unroll
    for (int s = 0; s < 10; s++)
#pragma unroll
        for (int e = 0; e < 4; e++) {
            float ex = __expf(v[s][e] - mx);
            v[s][e] = ex;                      // exp(-huge)=0 for pad lanes
            s0 += ex;
        }
#pragma unroll
    for (int off = 32; off; off >>= 1) s0 += __shfl_down(s0, off, 64);
    __syncthreads();                            // red[] reuse hazard
    if ((tid & 63) == 0) red[tid >> 6] = s0;
    __syncthreads();
    const float sum = red[0] + red[1] + red[2] + red[3];
    const float inv = 1.f / sum;
    const float thr = sum * 1e-7f;

    // write normalized probs + collect candidates (concept slots d < D_)
#pragma unroll
    for (int s = 0; s < 9; s++) {
        f32x4 p = v[s] * inv;
        *(f32x4*)(rowp + s * 1024 + tid * 4) = p;
#pragma unroll
        for (int e = 0; e < 4; e++)
            if (v[s][e] > thr) {
                int k = atomicAdd(&cnt, 1);
                if (k < CANDS) { cidx[k] = s * 1024 + tid * 4 + e; cp[k] = p[e]; }
            }
    }
    {
        const int base = 9216 + tid * 4;
#pragma unroll
        for (int e = 0; e < 4; e++) {
            int idx = base + e;
            if (idx <= D_) {
                float p = v[9][e] * inv;
                rowp[idx] = p;
                if (idx == D_) wslot = p;
                else if (v[9][e] > thr) {
                    int k = atomicAdd(&cnt, 1);
                    if (k < CANDS) { cidx[k] = idx; cp[k] = p; }
                }
            }
        }
    }
    __syncthreads();

    const float w = wslot;
    f32x4 a = w * ((const f32x4*)(desc + (size_t)row * H_))[tid];
    if (cnt <= CANDS) {
        const int k = cnt;
        for (int c = 0; c < k; c++)
            a += cp[c] * ((const f32x4*)(vocab + (size_t)cidx[c] * H_))[tid];
    } else {
        // overflow fallback (pathological rows only): scan normalized probs
        const float pthr = thr * inv;
        for (int d = 0; d < D_; d++) {
            float p = rowp[d];
            if (p > pthr) a += p * ((const f32x4*)(vocab + (size_t)d * H_))[tid];
        }
    }
    ((f32x4*)(out + (size_t)row * H_))[tid] = a;
}

// ---------- fallback (ws too small): exact fp32 logits, slow but correct ----------
__global__ __launch_bounds__(256)
void naive_logits_k(const float* __restrict__ vocab, const float* __restrict__ desc,
                    const float* __restrict__ defe, float* __restrict__ sim) {
    int d = blockIdx.x * 256 + threadIdx.x;
    if (d >= DP1) return;
    const float* vr = (d < D_) ? (vocab + (size_t)d * H_) : defe;
    const float* dr = desc + (size_t)blockIdx.y * H_;
    float s = 0.f;
    for (int h = 0; h < H_; h++) s = fmaf(dr[h], vr[h], s);
    sim[(size_t)blockIdx.y * DP1 + d] = s;
}

extern "C" void kernel_launch(void* const* d_in, const int* in_sizes, int n_in,
                              void* d_out, int out_size, void* d_ws, size_t ws_size,
                              hipStream_t stream) {
    (void)in_sizes; (void)n_in; (void)out_size;
    const float* vocab = (const float*)d_in[0];
    const float* desc  = (const float*)d_in[1];
    const float* defe  = (const float*)d_in[2];
    float* out = (float*)d_out;                          // concept: [4096][1024]
    float* sim = out + (size_t)BL * H_;                  // sim:     [4096][10001]

    // ws layout (bytes):
    //   desc_hi @ 0          (8,388,608)
    //   desc_lo @ 8,388,608  (8,388,608)
    //   fv_hi   @ 16,777,216 (20,971,520 = NPAD2*H_*2)
    //   fv_lo   @ 37,748,736 (20,971,520)          -> REQ1 = 58,720,256
    const size_t REQ1 = 58720256ull;
    char* ws = (char*)d_ws;

    if (ws_size >= REQ1) {
        u16* dhi = (u16*)(ws + 0);
        u16* dlo = (u16*)(ws + 8388608);
        u16* fhi = (u16*)(ws + 16777216);
        u16* flo = (u16*)(ws + 37748736);

        split_desc_k<<<16384, 256, 0, stream>>>(desc, dhi, dlo);
        split_fv_k<<<40960, 256, 0, stream>>>(vocab, defe, fhi, flo);
        gemm1_k<<<dim3(40, 32), 512, 0, stream>>>(dhi, dlo, fhi, flo, sim);
    } else {
        naive_logits_k<<<dim3(40, BL), 256, 0, stream>>>(vocab, desc, defe, sim);
    }
    softmax_gather_k<<<4096, 256, 0, stream>>>(sim, vocab, desc, out);
}

// Round 7
// 512.177 us; speedup vs baseline: 4.0096x; 1.0097x over previous
//
#include <hip/hip_runtime.h>
#include <stdint.h>

#define D_    10000
#define DP1   10001
#define NPAD2 10240      // 40 * 256 (padded vocab rows for GEMM1, N-tile 256)
#define H_    1024
#define BL    4096       // B * L
#define CANDS 1024       // candidate list capacity (p > 1e-7 of mass; typ. 2-6)

typedef float  f32x4  __attribute__((ext_vector_type(4)));
typedef __bf16 bf16x8 __attribute__((ext_vector_type(8)));
typedef unsigned short u16;
typedef u16    u16x8  __attribute__((ext_vector_type(8)));

// ---------- bf16 helpers (round-to-nearest-even) ----------
__device__ __forceinline__ u16 f2bf(float x) {
    union { float f; unsigned u; } v; v.f = x;
    unsigned r = v.u + 0x7FFFu + ((v.u >> 16) & 1u);
    return (u16)(r >> 16);
}
__device__ __forceinline__ float bf2f(u16 b) {
    union { float f; unsigned u; } v; v.u = ((unsigned)b) << 16;
    return v.f;
}

// async global -> LDS, 16B per lane (HW: wave-uniform base + lane*16)
#define GLOAD_LDS16(gsrc, ldst)                                             \
    __builtin_amdgcn_global_load_lds(                                       \
        (__attribute__((address_space(1))) void*)(void*)(gsrc),             \
        (__attribute__((address_space(3))) void*)(void*)(ldst), 16, 0, 0)

// History:
// R3: LDS chunk swizzle -> SQ_LDS_BANK_CONFLICT 2.07e7 -> 0.
// R6: 2-deep prefetch + counted vmcnt, (512,2), 96KB: 248-252us (PROVEN,
//   4 benches). MfmaUtil 46% is a derived-counter artifact; real MFMA-pipe
//   busy ~12.5%, latency/barrier-bound at ~1.5 blocks/CU.
// R7: 256^2 tile + 4-phase: REGRESSED (268us). Reverted.
// R8: sparse-gather epilogue replaced gemm2 pipeline: 692->648us, absmax
//   0.0313->0.0156.
// R9/R10: spill disasters. LESSON: WRITE_SIZE >> output size = scratch
//   spill; 16-live-frag K-step can't run at 4 waves/SIMD (needs ~156 regs).
// R11: consolidated R6 gemm1 + register gather: 517us. Non-gemm1 = 265us
//   vs ~90us roofline -> splits are scalar (Common-mistake #2) and
//   softmax_gather runs at only 20 waves/CU with 4 serial barrier phases.
// R12 (this): vectorize splits (8 elem/thread, u16x8 stores); softmax ->
//   1024 threads (VGPR<=64 -> 32 waves/CU), 12 elem/thread, same math.

// ---------- prep: split fp32 -> bf16 hi + lo (8 elements/thread) ----------
__global__ __launch_bounds__(256)
void split_desc_k(const float* __restrict__ desc, u16* __restrict__ hi, u16* __restrict__ lo) {
    size_t i = ((size_t)blockIdx.x * 256 + threadIdx.x) * 8;   // exactly BL*H_
    f32x4 x0 = *(const f32x4*)(desc + i);
    f32x4 x1 = *(const f32x4*)(desc + i + 4);
    u16x8 h, l;
#pragma unroll
    for (int e = 0; e < 4; e++) {
        h[e] = f2bf(x0[e]); l[e] = f2bf(x0[e] - bf2f(h[e]));
        h[4 + e] = f2bf(x1[e]); l[4 + e] = f2bf(x1[e] - bf2f(h[4 + e]));
    }
    *(u16x8*)(hi + i) = h;
    *(u16x8*)(lo + i) = l;
}

__global__ __launch_bounds__(256)
void split_fv_k(const float* __restrict__ vocab, const float* __restrict__ defe,
                u16* __restrict__ hi, u16* __restrict__ lo) {
    size_t i = ((size_t)blockIdx.x * 256 + threadIdx.x) * 8;   // exactly NPAD2*H_
    int d = (int)(i >> 10);                                    // 8-chunk never crosses rows
    f32x4 x0 = {0.f, 0.f, 0.f, 0.f}, x1 = {0.f, 0.f, 0.f, 0.f};
    if (d < D_) {
        x0 = *(const f32x4*)(vocab + i);
        x1 = *(const f32x4*)(vocab + i + 4);
    } else if (d == D_) {
        int h = (int)(i & 1023);
        x0 = *(const f32x4*)(defe + h);
        x1 = *(const f32x4*)(defe + h + 4);
    }
    u16x8 h8, l8;
#pragma unroll
    for (int e = 0; e < 4; e++) {
        h8[e] = f2bf(x0[e]); l8[e] = f2bf(x0[e] - bf2f(h8[e]));
        h8[4 + e] = f2bf(x1[e]); l8[4 + e] = f2bf(x1[e] - bf2f(h8[4 + e]));
    }
    *(u16x8*)(hi + i) = h8;
    *(u16x8*)(lo + i) = l8;
}

// ---------- GEMM1: logits = desc @ full_vocab^T, bf16 hi/lo split (3 MFMAs) ----------
// Tile 128(M) x 256(N), BK=32, 512 threads (8 waves, wave grid 2x4, 64x64/wave).
// Double-buffered LDS (96 KB), 2-deep prefetch with counted vmcnt.  [R6 form]

#define G1_MFMA(a, b, c) __builtin_amdgcn_mfma_f32_16x16x32_bf16((a), (b), (c), 0, 0, 0)

#define G1_STAGE(AhB, AlB, BhB, BlB, kk) do {                               \
    GLOAD_LDS16(a_h  + (kk), (char*)(AhB) + tid16);                         \
    GLOAD_LDS16(a_l  + (kk), (char*)(AlB) + tid16);                         \
    GLOAD_LDS16(b_h0 + (kk), (char*)(BhB) + tid16);                         \
    GLOAD_LDS16(b_h1 + (kk), (char*)(BhB) + tid16 + 8192);                  \
    GLOAD_LDS16(b_l0 + (kk), (char*)(BlB) + tid16);                         \
    GLOAD_LDS16(b_l1 + (kk), (char*)(BlB) + tid16 + 8192);                  \
} while (0)

// One K-tile: phase 0 = {ds_read 16 frags, 24 MFMA (i=0,1), lgkmcnt(0), barrier}
//             phase 1 = {STAGE t+2 -> this buffer, 24 MFMA (i=2,3), vmcnt(6), barrier}
// vmcnt(6): tile t+1's 6 loads (oldest) complete; tile t+2's 6 stay in flight.
#define G1_ITER(AhB, AlB, BhB, BlB, t) do {                                 \
    bf16x8 afh[4], afl[4], bfh[4], bfl[4];                                  \
    _Pragma("unroll")                                                       \
    for (int i = 0; i < 4; i++) {                                           \
        afh[i] = *(const bf16x8*)&AhB[aoff[i]];                             \
        afl[i] = *(const bf16x8*)&AlB[aoff[i]];                             \
        bfh[i] = *(const bf16x8*)&BhB[boff[i]];                             \
        bfl[i] = *(const bf16x8*)&BlB[boff[i]];                             \
    }                                                                       \
    __builtin_amdgcn_s_setprio(1);                                          \
    _Pragma("unroll")                                                       \
    for (int i = 0; i < 2; i++)                                             \
        _Pragma("unroll")                                                   \
        for (int j = 0; j < 4; j++) {                                       \
            acc[i][j] = G1_MFMA(afh[i], bfh[j], acc[i][j]);                 \
            acc[i][j] = G1_MFMA(afh[i], bfl[j], acc[i][j]);                 \
            acc[i][j] = G1_MFMA(afl[i], bfh[j], acc[i][j]);                 \
        }                                                                   \
    __builtin_amdgcn_s_setprio(0);                                          \
    asm volatile("s_waitcnt lgkmcnt(0)" ::: "memory");                      \
    __builtin_amdgcn_s_barrier();                                           \
    if ((t) + 2 < 32) G1_STAGE(AhB, AlB, BhB, BlB, ((t) + 2) * 32);         \
    __builtin_amdgcn_s_setprio(1);                                          \
    _Pragma("unroll")                                                       \
    for (int i = 2; i < 4; i++)                                             \
        _Pragma("unroll")                                                   \
        for (int j = 0; j < 4; j++) {                                       \
            acc[i][j] = G1_MFMA(afh[i], bfh[j], acc[i][j]);                 \
            acc[i][j] = G1_MFMA(afh[i], bfl[j], acc[i][j]);                 \
            acc[i][j] = G1_MFMA(afl[i], bfh[j], acc[i][j]);                 \
        }                                                                   \
    __builtin_amdgcn_s_setprio(0);                                          \
    if ((t) + 2 < 32)      asm volatile("s_waitcnt vmcnt(6)" ::: "memory"); \
    else if ((t) + 1 < 32) asm volatile("s_waitcnt vmcnt(0)" ::: "memory"); \
    __builtin_amdgcn_s_barrier();                                           \
} while (0)

__global__ __launch_bounds__(512, 2)
void gemm1_k(const u16* __restrict__ Ahg, const u16* __restrict__ Alg,
             const u16* __restrict__ Bhg, const u16* __restrict__ Blg,
             float* __restrict__ C) {
    // Two buffers as SEPARATE objects so the LDS-DMA waitcnt pass can
    // disambiguate: DMA into buf1 never forces a wait before ds_read of buf0.
    __shared__ u16 Ah0[128 * 32], Al0[128 * 32], Bh0[256 * 32], Bl0[256 * 32];
    __shared__ u16 Ah1[128 * 32], Al1[128 * 32], Bh1[256 * 32], Bl1[256 * 32];

    const int tid  = threadIdx.x;
    const int wave = tid >> 6, lane = tid & 63;
    const int wr = wave >> 2, wc = wave & 3;
    const int quad = lane >> 4, r16 = lane & 15;
    const int m0 = blockIdx.y * 128, n0 = blockIdx.x * 256;

    f32x4 zero = {0.f, 0.f, 0.f, 0.f};
    f32x4 acc[4][4];
#pragma unroll
    for (int i = 0; i < 4; i++)
#pragma unroll
        for (int j = 0; j < 4; j++) acc[i][j] = zero;

    // staging: thread t covers row t>>2, chunk t&3 (swizzled source column)
    const int arow = tid >> 2, achk = tid & 3;
    const int ascol = (achk ^ ((arow >> 1) & 3)) * 8;
    const u16* a_h = Ahg + (size_t)(m0 + arow) * H_ + ascol;
    const u16* a_l = Alg + (size_t)(m0 + arow) * H_ + ascol;
    const int brow0 = arow,        bscol0 = (achk ^ ((brow0 >> 1) & 3)) * 8;
    const int brow1 = 128 + arow,  bscol1 = (achk ^ ((brow1 >> 1) & 3)) * 8;
    const u16* b_h0 = Bhg + (size_t)(n0 + brow0) * H_ + bscol0;
    const u16* b_h1 = Bhg + (size_t)(n0 + brow1) * H_ + bscol1;
    const u16* b_l0 = Blg + (size_t)(n0 + brow0) * H_ + bscol0;
    const u16* b_l1 = Blg + (size_t)(n0 + brow1) * H_ + bscol1;
    const int tid16 = tid * 16;
    const int aswz = (r16 >> 1) & 3;

    // fragment LDS element offsets (same for both buffers)
    int aoff[4], boff[4];
#pragma unroll
    for (int i = 0; i < 4; i++) {
        aoff[i] = (wr * 64 + i * 16 + r16) * 32 + ((quad ^ aswz) * 8);
        boff[i] = (wc * 64 + i * 16 + r16) * 32 + ((quad ^ aswz) * 8);
    }

    // Prologue: stage tiles 0 and 1; wait only for tile 0 (vmcnt(6)).
    G1_STAGE(Ah0, Al0, Bh0, Bl0, 0);
    G1_STAGE(Ah1, Al1, Bh1, Bl1, 32);
    asm volatile("s_waitcnt vmcnt(6)" ::: "memory");
    __builtin_amdgcn_s_barrier();

    for (int t = 0; t < 32; t += 2) {
        G1_ITER(Ah0, Al0, Bh0, Bl0, t);
        G1_ITER(Ah1, Al1, Bh1, Bl1, t + 1);
    }

    // C/D layout: row = quad*4 + reg, col = lane&15
#pragma unroll
    for (int i = 0; i < 4; i++) {
        int gm = m0 + wr * 64 + i * 16 + quad * 4;
#pragma unroll
        for (int j = 0; j < 4; j++) {
            int gn = n0 + wc * 64 + j * 16 + r16;
            if (gn < DP1) {
#pragma unroll
                for (int reg = 0; reg < 4; reg++)
                    C[(size_t)(gm + reg) * DP1 + gn] = acc[i][j][reg];
            }
        }
    }
}

// ---------- fused softmax + sparse gather epilogue (1024 threads, 12 elem/thread) ----------
// One block per (b,l) row; thread t holds elements {s*4096 + t*4 + e}, s<3.
// concept[row] = p[D_]*desc[row] + sum_{d: e_d > 1e-7*Z} p_d * vocab[d].
// Dropped mass <= 1e-3 worst case; typically ~e^-16 (logits ~ N(0,32^2)).
__global__ __launch_bounds__(1024)
void softmax_gather_k(float* __restrict__ sim, const float* __restrict__ vocab,
                      const float* __restrict__ desc, float* __restrict__ out) {
    __shared__ float red[16];
    __shared__ float wslot;
    __shared__ int   cnt;
    __shared__ int   cidx[CANDS];
    __shared__ float cp[CANDS];
    const int tid = threadIdx.x;
    const int row = blockIdx.x;
    float* rowp = sim + (size_t)row * DP1;
    if (tid == 0) cnt = 0;

    const int base2 = 8192 + tid * 4;
    f32x4 v0 = *(const f32x4*)(rowp + tid * 4);
    f32x4 v1 = *(const f32x4*)(rowp + 4096 + tid * 4);
    f32x4 v2;
    if (base2 + 3 <= D_) {
        v2 = *(const f32x4*)(rowp + base2);
    } else {
#pragma unroll
        for (int e = 0; e < 4; e++)
            v2[e] = (base2 + e <= D_) ? rowp[base2 + e] : -3.4e38f;
    }

    float mx = -3.4e38f;
#pragma unroll
    for (int e = 0; e < 4; e++) mx = fmaxf(mx, fmaxf(v0[e], fmaxf(v1[e], v2[e])));
#pragma unroll
    for (int off = 32; off; off >>= 1) mx = fmaxf(mx, __shfl_down(mx, off, 64));
    if ((tid & 63) == 0) red[tid >> 6] = mx;
    __syncthreads();
#pragma unroll
    for (int w = 0; w < 16; w++) mx = fmaxf(mx, red[w]);

    float s0 = 0.f;
#pragma unroll
    for (int e = 0; e < 4; e++) {
        v0[e] = __expf(v0[e] - mx); s0 += v0[e];
        v1[e] = __expf(v1[e] - mx); s0 += v1[e];
        v2[e] = __expf(v2[e] - mx); s0 += v2[e];   // exp(-huge)=0 for pad
    }
#pragma unroll
    for (int off = 32; off; off >>= 1) s0 += __shfl_down(s0, off, 64);
    __syncthreads();                                // red[] reuse hazard
    if ((tid & 63) == 0) red[tid >> 6] = s0;
    __syncthreads();
    float sum = 0.f;
#pragma unroll
    for (int w = 0; w < 16; w++) sum += red[w];
    const float inv = 1.f / sum;
    const float thr = sum * 1e-7f;

    // write normalized probs + collect candidates (concept slots d < D_)
    {
        f32x4 p0 = v0 * inv;
        *(f32x4*)(rowp + tid * 4) = p0;
#pragma unroll
        for (int e = 0; e < 4; e++)
            if (v0[e] > thr) {
                int k = atomicAdd(&cnt, 1);
                if (k < CANDS) { cidx[k] = tid * 4 + e; cp[k] = p0[e]; }
            }
        f32x4 p1 = v1 * inv;
        *(f32x4*)(rowp + 4096 + tid * 4) = p1;
#pragma unroll
        for (int e = 0; e < 4; e++)
            if (v1[e] > thr) {
                int k = atomicAdd(&cnt, 1);
                if (k < CANDS) { cidx[k] = 4096 + tid * 4 + e; cp[k] = p1[e]; }
            }
#pragma unroll
        for (int e = 0; e < 4; e++) {
            int idx = base2 + e;
            if (idx <= D_) {
                float p = v2[e] * inv;
                rowp[idx] = p;
                if (idx == D_) wslot = p;
                else if (v2[e] > thr) {
                    int k = atomicAdd(&cnt, 1);
                    if (k < CANDS) { cidx[k] = idx; cp[k] = p; }
                }
            }
        }
    }
    __syncthreads();

    // gather: thread t owns H-column t (scalar, wave reads 256B contiguous)
    const float w = wslot;
    float a = w * desc[(size_t)row * H_ + tid];
    if (cnt <= CANDS) {
        const int k = cnt;
        for (int c = 0; c < k; c++)
            a += cp[c] * vocab[(size_t)cidx[c] * H_ + tid];
    } else {
        // overflow fallback (pathological rows only): scan normalized probs
        const float pthr = thr * inv;
        for (int d = 0; d < D_; d++) {
            float p = rowp[d];
            if (p > pthr) a += p * vocab[(size_t)d * H_ + tid];
        }
    }
    out[(size_t)row * H_ + tid] = a;
}

// ---------- fallback (ws too small): exact fp32 logits, slow but correct ----------
__global__ __launch_bounds__(256)
void naive_logits_k(const float* __restrict__ vocab, const float* __restrict__ desc,
                    const float* __restrict__ defe, float* __restrict__ sim) {
    int d = blockIdx.x * 256 + threadIdx.x;
    if (d >= DP1) return;
    const float* vr = (d < D_) ? (vocab + (size_t)d * H_) : defe;
    const float* dr = desc + (size_t)blockIdx.y * H_;
    float s = 0.f;
    for (int h = 0; h < H_; h++) s = fmaf(dr[h], vr[h], s);
    sim[(size_t)blockIdx.y * DP1 + d] = s;
}

extern "C" void kernel_launch(void* const* d_in, const int* in_sizes, int n_in,
                              void* d_out, int out_size, void* d_ws, size_t ws_size,
                              hipStream_t stream) {
    (void)in_sizes; (void)n_in; (void)out_size;
    const float* vocab = (const float*)d_in[0];
    const float* desc  = (const float*)d_in[1];
    const float* defe  = (const float*)d_in[2];
    float* out = (float*)d_out;                          // concept: [4096][1024]
    float* sim = out + (size_t)BL * H_;                  // sim:     [4096][10001]

    // ws layout (bytes):
    //   desc_hi @ 0          (8,388,608)
    //   desc_lo @ 8,388,608  (8,388,608)
    //   fv_hi   @ 16,777,216 (20,971,520 = NPAD2*H_*2)
    //   fv_lo   @ 37,748,736 (20,971,520)          -> REQ1 = 58,720,256
    const size_t REQ1 = 58720256ull;
    char* ws = (char*)d_ws;

    if (ws_size >= REQ1) {
        u16* dhi = (u16*)(ws + 0);
        u16* dlo = (u16*)(ws + 8388608);
        u16* fhi = (u16*)(ws + 16777216);
        u16* flo = (u16*)(ws + 37748736);

        split_desc_k<<<2048, 256, 0, stream>>>(desc, dhi, dlo);
        split_fv_k<<<5120, 256, 0, stream>>>(vocab, defe, fhi, flo);
        gemm1_k<<<dim3(40, 32), 512, 0, stream>>>(dhi, dlo, fhi, flo, sim);
    } else {
        naive_logits_k<<<dim3(40, BL), 256, 0, stream>>>(vocab, desc, defe, sim);
    }
    softmax_gather_k<<<4096, 1024, 0, stream>>>(sim, vocab, desc, out);
}